// Round 1
// baseline (420.481 us; speedup 1.0000x reference)
//
#include <hip/hip_runtime.h>

#define S_LEN 4096
#define DMODEL 1024
#define NQKV 3072
#define NHEAD 16

typedef __attribute__((ext_vector_type(8))) short s16x8;
typedef __attribute__((ext_vector_type(4))) float f32x4;

__device__ inline unsigned short f2bf(float f){
  unsigned u = __builtin_bit_cast(unsigned, f);
  u += 0x7FFFu + ((u >> 16) & 1u);
  return (unsigned short)(u >> 16);
}

__device__ inline void gload_lds16(const void* g, void* l){
  __builtin_amdgcn_global_load_lds(
    (const __attribute__((address_space(1))) void*)g,
    (__attribute__((address_space(3))) void*)l, 16, 0, 0);
}

// ---- pack: x fp32 -> bf16 ----
__global__ __launch_bounds__(256) void pack_x_kern(const float* __restrict__ x,
                                                   unsigned short* __restrict__ xb){
  int i = (blockIdx.x * 256 + threadIdx.x) * 4;
  float4 v = *(const float4*)(x + i);
  ushort4 o;
  o.x = f2bf(v.x); o.y = f2bf(v.y); o.z = f2bf(v.z); o.w = f2bf(v.w);
  *(ushort4*)(xb + i) = o;
}

// ---- pack: wq/wk/wv [H][D][Dh] -> wt [3072][1024] (B^T layout), bias [3072] ----
// q columns pre-scaled by 0.125*log2(e) so attention softmax can use exp2 directly.
__global__ __launch_bounds__(256) void pack_wqkv_kern(
    const float* __restrict__ wq, const float* __restrict__ bq,
    const float* __restrict__ wk, const float* __restrict__ bk,
    const float* __restrict__ wv, const float* __restrict__ bv,
    unsigned short* __restrict__ wt, float* __restrict__ bias){
  int idx = blockIdx.x * 256 + threadIdx.x;      // [0, 3*1024*1024)
  int which = idx >> 20;
  int rem = idx & 1048575;
  int e = rem & 63;
  int d = (rem >> 6) & 1023;
  int h = rem >> 16;
  const float* w = which == 0 ? wq : which == 1 ? wk : wv;
  const float* b = which == 0 ? bq : which == 1 ? bk : bv;
  float scale = which == 0 ? 0.18033688011112042f : 1.0f;  // 0.125 * log2(e)
  float val = w[(h * 1024 + d) * 64 + e] * scale;
  int n = which * 1024 + h * 64 + e;
  wt[(size_t)n * 1024 + d] = f2bf(val);
  if (d == 0) bias[n] = b[h * 64 + e] * scale;
}

// ---- pack: wo [D][D] -> wot [N][K] bf16 ----
__global__ __launch_bounds__(256) void pack_wo_kern(const float* __restrict__ wo,
                                                    unsigned short* __restrict__ wot){
  int idx = blockIdx.x * 256 + threadIdx.x;      // [0, 1M)
  int n = idx & 1023, d = idx >> 10;
  wot[(size_t)n * 1024 + d] = f2bf(wo[(size_t)d * 1024 + n]);
}

// ---- bf16 MFMA GEMM: C[M,N] = A[M,K] * Bt[N,K]^T + bias, 128x128 tile, BK=64 ----
template <bool OUT_BF16>
__global__ __launch_bounds__(256) void gemm_bt(const unsigned short* __restrict__ A,
                                               const unsigned short* __restrict__ Bt,
                                               const float* __restrict__ bias,
                                               void* __restrict__ Cout,
                                               int M, int N, int K){
  __shared__ unsigned short As[128 * 64];
  __shared__ unsigned short Bs[128 * 64];
  int tid = threadIdx.x;
  int lane = tid & 63, w = tid >> 6;
  int wr = w >> 1, wc = w & 1;
  int m0 = blockIdx.y * 128, n0 = blockIdx.x * 128;
  f32x4 zero = {0.f, 0.f, 0.f, 0.f};
  f32x4 acc[4][4];
#pragma unroll
  for (int i = 0; i < 4; i++)
#pragma unroll
    for (int j = 0; j < 4; j++) acc[i][j] = zero;

  for (int ks = 0; ks < K; ks += 64){
#pragma unroll
    for (int i = 0; i < 4; i++){
      int u = i * 256 + tid;
      int row = u >> 3, c = u & 7;
      gload_lds16(A + ((size_t)(m0 + row) * K + ks + ((c ^ (row & 7)) << 3)), &As[u * 8]);
    }
#pragma unroll
    for (int i = 0; i < 4; i++){
      int u = i * 256 + tid;
      int row = u >> 3, c = u & 7;
      gload_lds16(Bt + ((size_t)(n0 + row) * K + ks + ((c ^ (row & 7)) << 3)), &Bs[u * 8]);
    }
    __syncthreads();
#pragma unroll
    for (int kk = 0; kk < 2; kk++){
      s16x8 af[4], bfr[4];
#pragma unroll
      for (int i = 0; i < 4; i++){
        int ra = wr * 64 + i * 16 + (lane & 15);
        int ca = kk * 4 + (lane >> 4);
        af[i] = *(const s16x8*)&As[ra * 64 + ((ca ^ (ra & 7)) << 3)];
        int rb = wc * 64 + i * 16 + (lane & 15);
        bfr[i] = *(const s16x8*)&Bs[rb * 64 + ((ca ^ (rb & 7)) << 3)];
      }
#pragma unroll
      for (int i = 0; i < 4; i++)
#pragma unroll
        for (int j = 0; j < 4; j++)
          acc[i][j] = __builtin_amdgcn_mfma_f32_16x16x32_bf16(af[i], bfr[j], acc[i][j], 0, 0, 0);
    }
    __syncthreads();
  }
#pragma unroll
  for (int i = 0; i < 4; i++)
#pragma unroll
    for (int j = 0; j < 4; j++){
      int col = n0 + wc * 64 + j * 16 + (lane & 15);
      float bv = bias[col];
#pragma unroll
      for (int r = 0; r < 4; r++){
        int row = m0 + wr * 64 + i * 16 + ((lane >> 4) << 2) + r;
        float v = acc[i][j][r] + bv;
        if (OUT_BF16) ((unsigned short*)Cout)[(size_t)row * N + col] = f2bf(v);
        else          ((float*)Cout)[(size_t)row * N + col] = v;
      }
    }
}

// ---- flash attention: qkv [4096][3072] bf16 (q pre-scaled), out concat [4096][1024] bf16 ----
__global__ __launch_bounds__(256) void attn_kern(const unsigned short* __restrict__ qkv,
                                                 unsigned short* __restrict__ concat){
  __shared__ unsigned short Ks[64 * 64];   // [t][e] swizzled
  __shared__ unsigned short Vs[64 * 64];   // [t][e] linear
  __shared__ unsigned short Ps[4][16 * 64]; // per-wave P, swizzled
  int tid = threadIdx.x, lane = tid & 63, w = tid >> 6;
  int h = blockIdx.y;
  int q0 = blockIdx.x * 64 + w * 16;
  const int LD = NQKV;
  s16x8 qa[2];
#pragma unroll
  for (int kc = 0; kc < 2; kc++)
    qa[kc] = *(const s16x8*)&qkv[(size_t)(q0 + (lane & 15)) * LD + h * 64 + kc * 32 + ((lane >> 4) << 3)];
  f32x4 zero = {0.f, 0.f, 0.f, 0.f};
  f32x4 o[4];
  float m_run[4], l_run[4];
#pragma unroll
  for (int r = 0; r < 4; r++){ m_run[r] = -1e30f; l_run[r] = 0.f; }
#pragma unroll
  for (int nc = 0; nc < 4; nc++) o[nc] = zero;

  for (int kt = 0; kt < S_LEN / 64; kt++){
    int t0 = kt * 64;
#pragma unroll
    for (int i = 0; i < 2; i++){
      int u = i * 256 + tid;
      int row = u >> 3, c = u & 7;
      gload_lds16(&qkv[(size_t)(t0 + row) * LD + 1024 + h * 64 + ((c ^ (row & 7)) << 3)], &Ks[u * 8]);
      gload_lds16(&qkv[(size_t)(t0 + row) * LD + 2048 + h * 64 + (c << 3)], &Vs[u * 8]);
    }
    __syncthreads();
    // scores S[16q x 64t] in C-layout: col=t=lane&15 (per 16-tile), row=q=(lane>>4)*4+r
    f32x4 s[4];
#pragma unroll
    for (int ct = 0; ct < 4; ct++){
      f32x4 a = zero;
#pragma unroll
      for (int kc = 0; kc < 2; kc++){
        int tr = ct * 16 + (lane & 15);
        int c = kc * 4 + (lane >> 4);
        s16x8 kb = *(const s16x8*)&Ks[tr * 64 + ((c ^ (tr & 7)) << 3)];
        a = __builtin_amdgcn_mfma_f32_16x16x32_bf16(qa[kc], kb, a, 0, 0, 0);
      }
      s[ct] = a;
    }
    // online softmax (base-2 domain; q was pre-scaled by 0.125*log2e)
    float mt[4], mn[4], sc[4], lt[4];
#pragma unroll
    for (int r = 0; r < 4; r++)
      mt[r] = fmaxf(fmaxf(s[0][r], s[1][r]), fmaxf(s[2][r], s[3][r]));
#pragma unroll
    for (int r = 0; r < 4; r++){
      mt[r] = fmaxf(mt[r], __shfl_xor(mt[r], 1));
      mt[r] = fmaxf(mt[r], __shfl_xor(mt[r], 2));
      mt[r] = fmaxf(mt[r], __shfl_xor(mt[r], 4));
      mt[r] = fmaxf(mt[r], __shfl_xor(mt[r], 8));
    }
    float ps[4][4];
#pragma unroll
    for (int r = 0; r < 4; r++){
      mn[r] = fmaxf(m_run[r], mt[r]);
      sc[r] = __builtin_amdgcn_exp2f(m_run[r] - mn[r]);
      lt[r] = 0.f;
    }
#pragma unroll
    for (int ct = 0; ct < 4; ct++)
#pragma unroll
      for (int r = 0; r < 4; r++){
        float p = __builtin_amdgcn_exp2f(s[ct][r] - mn[r]);
        ps[ct][r] = p;
        lt[r] += p;
      }
#pragma unroll
    for (int r = 0; r < 4; r++){
      lt[r] += __shfl_xor(lt[r], 1);
      lt[r] += __shfl_xor(lt[r], 2);
      lt[r] += __shfl_xor(lt[r], 4);
      lt[r] += __shfl_xor(lt[r], 8);
      l_run[r] = l_run[r] * sc[r] + lt[r];
      m_run[r] = mn[r];
    }
#pragma unroll
    for (int nc = 0; nc < 4; nc++)
#pragma unroll
      for (int r = 0; r < 4; r++) o[nc][r] *= sc[r];
    // P -> per-wave LDS (swizzled), then A-frag reads (same-wave DS ops are in-order)
#pragma unroll
    for (int ct = 0; ct < 4; ct++)
#pragma unroll
      for (int r = 0; r < 4; r++){
        int qr = ((lane >> 4) << 2) + r;
        int t = ct * 16 + (lane & 15);
        int c = t >> 3;
        Ps[w][qr * 64 + (((c ^ (qr & 7)) << 3) | (t & 7))] = f2bf(ps[ct][r]);
      }
#pragma unroll
    for (int kc = 0; kc < 2; kc++){
      int qr = lane & 15;
      int c = kc * 4 + (lane >> 4);
      s16x8 pa = *(const s16x8*)&Ps[w][qr * 64 + ((c ^ (qr & 7)) << 3)];
#pragma unroll
      for (int nc = 0; nc < 4; nc++){
        union { s16x8 v; short a[8]; } vb;
        int tb = kc * 32 + ((lane >> 4) << 3);
        int e  = nc * 16 + (lane & 15);
#pragma unroll
        for (int j = 0; j < 8; j++) vb.a[j] = (short)Vs[(tb + j) * 64 + e];
        o[nc] = __builtin_amdgcn_mfma_f32_16x16x32_bf16(pa, vb.v, o[nc], 0, 0, 0);
      }
    }
    __syncthreads();
  }
  float inv[4];
#pragma unroll
  for (int r = 0; r < 4; r++) inv[r] = 1.0f / l_run[r];
#pragma unroll
  for (int nc = 0; nc < 4; nc++)
#pragma unroll
    for (int r = 0; r < 4; r++){
      int row = q0 + ((lane >> 4) << 2) + r;
      int col = h * 64 + nc * 16 + (lane & 15);
      concat[(size_t)row * DMODEL + col] = f2bf(o[nc][r] * inv[r]);
    }
}

extern "C" void kernel_launch(void* const* d_in, const int* in_sizes, int n_in,
                              void* d_out, int out_size, void* d_ws, size_t ws_size,
                              hipStream_t stream){
  const float* x  = (const float*)d_in[0];
  const float* wq = (const float*)d_in[1];
  const float* bq = (const float*)d_in[2];
  const float* wk = (const float*)d_in[3];
  const float* bk = (const float*)d_in[4];
  const float* wv = (const float*)d_in[5];
  const float* bv = (const float*)d_in[6];
  const float* wo = (const float*)d_in[7];
  const float* bo = (const float*)d_in[8];
  char* ws = (char*)d_ws;
  // layout (bytes): xb 8.39M | wqkvt 6.29M | wot 2.10M | biasq 12K(+pad) | qkv 25.2M | concat 8.39M  => ~50.4MB
  unsigned short* xb     = (unsigned short*)(ws + 0);
  unsigned short* wqkvt  = (unsigned short*)(ws + 8388608);
  unsigned short* wot    = (unsigned short*)(ws + 14680064);
  float*          biasq  = (float*)(ws + 16777216);
  unsigned short* qkv    = (unsigned short*)(ws + 16842752);
  unsigned short* concat = (unsigned short*)(ws + 42008576);
  float* out = (float*)d_out;

  pack_x_kern<<<4096, 256, 0, stream>>>(x, xb);
  pack_wqkv_kern<<<12288, 256, 0, stream>>>(wq, bq, wk, bk, wv, bv, wqkvt, biasq);
  pack_wo_kern<<<4096, 256, 0, stream>>>(wo, wot);
  gemm_bt<true><<<dim3(24, 32), 256, 0, stream>>>(xb, wqkvt, biasq, qkv, 4096, 3072, 1024);
  attn_kern<<<dim3(64, 16), 256, 0, stream>>>(qkv, concat);
  gemm_bt<false><<<dim3(8, 32), 256, 0, stream>>>(concat, wot, bo, out, 4096, 1024, 1024);
}

// Round 2
// 314.824 us; speedup vs baseline: 1.3356x; 1.3356x over previous
//
#include <hip/hip_runtime.h>

#define S_LEN 4096
#define DMODEL 1024
#define NQKV 3072
#define NHEAD 16

typedef __attribute__((ext_vector_type(8))) short s16x8;
typedef __attribute__((ext_vector_type(4))) float f32x4;

__device__ inline unsigned short f2bf(float f){
  unsigned u = __builtin_bit_cast(unsigned, f);
  u += 0x7FFFu + ((u >> 16) & 1u);
  return (unsigned short)(u >> 16);
}

__device__ inline void gload_lds16(const void* g, void* l){
  __builtin_amdgcn_global_load_lds(
    (const __attribute__((address_space(1))) void*)g,
    (__attribute__((address_space(3))) void*)l, 16, 0, 0);
}

// ---- pack: x fp32 -> bf16 ----
__global__ __launch_bounds__(256) void pack_x_kern(const float* __restrict__ x,
                                                   unsigned short* __restrict__ xb){
  int i = (blockIdx.x * 256 + threadIdx.x) * 4;
  float4 v = *(const float4*)(x + i);
  ushort4 o;
  o.x = f2bf(v.x); o.y = f2bf(v.y); o.z = f2bf(v.z); o.w = f2bf(v.w);
  *(ushort4*)(xb + i) = o;
}

// ---- pack: wq/wk/wv [H][D][Dh] -> wt [3072][1024] (B^T layout), bias [3072] ----
// q columns pre-scaled by 0.125*log2(e) so attention softmax can use exp2 directly.
__global__ __launch_bounds__(256) void pack_wqkv_kern(
    const float* __restrict__ wq, const float* __restrict__ bq,
    const float* __restrict__ wk, const float* __restrict__ bk,
    const float* __restrict__ wv, const float* __restrict__ bv,
    unsigned short* __restrict__ wt, float* __restrict__ bias){
  int idx = blockIdx.x * 256 + threadIdx.x;      // [0, 3*1024*1024)
  int which = idx >> 20;
  int rem = idx & 1048575;
  int e = rem & 63;
  int d = (rem >> 6) & 1023;
  int h = rem >> 16;
  const float* w = which == 0 ? wq : which == 1 ? wk : wv;
  const float* b = which == 0 ? bq : which == 1 ? bk : bv;
  float scale = which == 0 ? 0.18033688011112042f : 1.0f;  // 0.125 * log2(e)
  float val = w[(h * 1024 + d) * 64 + e] * scale;
  int n = which * 1024 + h * 64 + e;
  wt[(size_t)n * 1024 + d] = f2bf(val);
  if (d == 0) bias[n] = b[h * 64 + e] * scale;
}

// ---- pack: wo [D][D] -> wot [N][K] bf16 ----
__global__ __launch_bounds__(256) void pack_wo_kern(const float* __restrict__ wo,
                                                    unsigned short* __restrict__ wot){
  int idx = blockIdx.x * 256 + threadIdx.x;      // [0, 1M)
  int n = idx & 1023, d = idx >> 10;
  wot[(size_t)n * 1024 + d] = f2bf(wo[(size_t)d * 1024 + n]);
}

// ---- transpose V columns of qkv: qkv[t][2048+c] -> vT[c][t]  (c in [0,1024)) ----
__global__ __launch_bounds__(256) void transpose_v_kern(const unsigned short* __restrict__ qkv,
                                                        unsigned short* __restrict__ vT){
  __shared__ unsigned short tile[64][65];
  int t0 = blockIdx.x * 64, c0 = blockIdx.y * 64;
  int tid = threadIdx.x;
  int r = tid >> 2;
#pragma unroll
  for (int p = 0; p < 2; p++){
    int col = (tid & 3) * 16 + p * 8;
    s16x8 v = *(const s16x8*)&qkv[(size_t)(t0 + r) * NQKV + 2048 + c0 + col];
#pragma unroll
    for (int j = 0; j < 8; j++) tile[r][col + j] = (unsigned short)v[j];
  }
  __syncthreads();
  int c = tid >> 2;
#pragma unroll
  for (int p = 0; p < 2; p++){
    int tt = (tid & 3) * 16 + p * 8;
    union { s16x8 v; unsigned short a[8]; } u;
#pragma unroll
    for (int j = 0; j < 8; j++) u.a[j] = tile[tt + j][c];
    *(s16x8*)&vT[(size_t)(c0 + c) * S_LEN + t0 + tt] = u.v;
  }
}

// ---- bf16 MFMA GEMM: C[M,N] = A[M,K] * Bt[N,K]^T + bias, 128x128 tile, BK=64 ----
template <bool OUT_BF16>
__global__ __launch_bounds__(256) void gemm_bt(const unsigned short* __restrict__ A,
                                               const unsigned short* __restrict__ Bt,
                                               const float* __restrict__ bias,
                                               void* __restrict__ Cout,
                                               int M, int N, int K){
  __shared__ unsigned short As[128 * 64];
  __shared__ unsigned short Bs[128 * 64];
  int tid = threadIdx.x;
  int lane = tid & 63, w = tid >> 6;
  int wr = w >> 1, wc = w & 1;
  int m0 = blockIdx.y * 128, n0 = blockIdx.x * 128;
  f32x4 zero = {0.f, 0.f, 0.f, 0.f};
  f32x4 acc[4][4];
#pragma unroll
  for (int i = 0; i < 4; i++)
#pragma unroll
    for (int j = 0; j < 4; j++) acc[i][j] = zero;

  for (int ks = 0; ks < K; ks += 64){
#pragma unroll
    for (int i = 0; i < 4; i++){
      int u = i * 256 + tid;
      int row = u >> 3, c = u & 7;
      gload_lds16(A + ((size_t)(m0 + row) * K + ks + ((c ^ (row & 7)) << 3)), &As[u * 8]);
    }
#pragma unroll
    for (int i = 0; i < 4; i++){
      int u = i * 256 + tid;
      int row = u >> 3, c = u & 7;
      gload_lds16(Bt + ((size_t)(n0 + row) * K + ks + ((c ^ (row & 7)) << 3)), &Bs[u * 8]);
    }
    __syncthreads();
#pragma unroll
    for (int kk = 0; kk < 2; kk++){
      s16x8 af[4], bfr[4];
#pragma unroll
      for (int i = 0; i < 4; i++){
        int ra = wr * 64 + i * 16 + (lane & 15);
        int ca = kk * 4 + (lane >> 4);
        af[i] = *(const s16x8*)&As[ra * 64 + ((ca ^ (ra & 7)) << 3)];
        int rb = wc * 64 + i * 16 + (lane & 15);
        bfr[i] = *(const s16x8*)&Bs[rb * 64 + ((ca ^ (rb & 7)) << 3)];
      }
#pragma unroll
      for (int i = 0; i < 4; i++)
#pragma unroll
        for (int j = 0; j < 4; j++)
          acc[i][j] = __builtin_amdgcn_mfma_f32_16x16x32_bf16(af[i], bfr[j], acc[i][j], 0, 0, 0);
    }
    __syncthreads();
  }
#pragma unroll
  for (int i = 0; i < 4; i++)
#pragma unroll
    for (int j = 0; j < 4; j++){
      int col = n0 + wc * 64 + j * 16 + (lane & 15);
      float bv = bias[col];
#pragma unroll
      for (int r = 0; r < 4; r++){
        int row = m0 + wr * 64 + i * 16 + ((lane >> 4) << 2) + r;
        float v = acc[i][j][r] + bv;
        if (OUT_BF16) ((unsigned short*)Cout)[(size_t)row * N + col] = f2bf(v);
        else          ((float*)Cout)[(size_t)row * N + col] = v;
      }
    }
}

// ---- flash attention v2: 4 waves x 32 q-rows, KVBLK=64, V from vT, K/V double-buffered ----
__global__ __launch_bounds__(256) void attn_kern(const unsigned short* __restrict__ qkv,
                                                 const unsigned short* __restrict__ vT,
                                                 unsigned short* __restrict__ concat){
  __shared__ unsigned short Ks[2][64 * 64];   // [t][d] swizzled rows
  __shared__ unsigned short Vs[2][64 * 64];   // [e][t] swizzled rows
  __shared__ unsigned short Ps[4][32 * 64];   // per-wave P [qrow][t], swizzled
  int tid = threadIdx.x, lane = tid & 63, w = tid >> 6;
  int h = blockIdx.y;
  int q0 = blockIdx.x * 128 + w * 32;
  // Q fragments (pre-scaled by 0.125*log2e in pack)
  s16x8 qa[2][2];
#pragma unroll
  for (int qt = 0; qt < 2; qt++)
#pragma unroll
    for (int kc = 0; kc < 2; kc++)
      qa[qt][kc] = *(const s16x8*)&qkv[(size_t)(q0 + qt * 16 + (lane & 15)) * NQKV + h * 64 + kc * 32 + ((lane >> 4) << 3)];
  f32x4 zero = {0.f, 0.f, 0.f, 0.f};
  f32x4 o[2][4];
  float m_run[2][4], l_run[2][4];
#pragma unroll
  for (int qt = 0; qt < 2; qt++)
#pragma unroll
    for (int r = 0; r < 4; r++){ m_run[qt][r] = -1e30f; l_run[qt][r] = 0.f; }
#pragma unroll
  for (int qt = 0; qt < 2; qt++)
#pragma unroll
    for (int nc = 0; nc < 4; nc++) o[qt][nc] = zero;

#define STAGE(buf, kt) do { \
    int t0_ = (kt) * 64; \
    _Pragma("unroll") \
    for (int i_ = 0; i_ < 2; i_++){ \
      int u_ = i_ * 256 + tid; \
      int row_ = u_ >> 3, c_ = u_ & 7; \
      gload_lds16(&qkv[(size_t)(t0_ + row_) * NQKV + 1024 + h * 64 + ((c_ ^ (row_ & 7)) << 3)], &Ks[buf][u_ * 8]); \
      gload_lds16(&vT[(size_t)(h * 64 + row_) * S_LEN + t0_ + ((c_ ^ (row_ & 7)) << 3)], &Vs[buf][u_ * 8]); \
    } } while (0)

  STAGE(0, 0);
  __syncthreads();
  int cur = 0;
  for (int kt = 0; kt < S_LEN / 64; kt++){
    if (kt + 1 < S_LEN / 64) STAGE(cur ^ 1, kt + 1);
    const unsigned short* Kc = Ks[cur];
    const unsigned short* Vc = Vs[cur];
    // ---- QK^T: S[2qt][4ct] ----
    f32x4 s[2][4];
#pragma unroll
    for (int qt = 0; qt < 2; qt++)
#pragma unroll
      for (int ct = 0; ct < 4; ct++) s[qt][ct] = zero;
#pragma unroll
    for (int ct = 0; ct < 4; ct++)
#pragma unroll
      for (int kc = 0; kc < 2; kc++){
        int tr = ct * 16 + (lane & 15);
        int c = kc * 4 + (lane >> 4);
        s16x8 kb = *(const s16x8*)&Kc[tr * 64 + ((c ^ (tr & 7)) << 3)];
#pragma unroll
        for (int qt = 0; qt < 2; qt++)
          s[qt][ct] = __builtin_amdgcn_mfma_f32_16x16x32_bf16(qa[qt][kc], kb, s[qt][ct], 0, 0, 0);
      }
    // ---- online softmax (base-2 domain) + P store ----
#pragma unroll
    for (int qt = 0; qt < 2; qt++){
      float mt[4], mn[4], sc[4], lt[4];
#pragma unroll
      for (int r = 0; r < 4; r++){
        mt[r] = fmaxf(fmaxf(s[qt][0][r], s[qt][1][r]), fmaxf(s[qt][2][r], s[qt][3][r]));
        mt[r] = fmaxf(mt[r], __shfl_xor(mt[r], 1));
        mt[r] = fmaxf(mt[r], __shfl_xor(mt[r], 2));
        mt[r] = fmaxf(mt[r], __shfl_xor(mt[r], 4));
        mt[r] = fmaxf(mt[r], __shfl_xor(mt[r], 8));
        mn[r] = fmaxf(m_run[qt][r], mt[r]);
        sc[r] = __builtin_amdgcn_exp2f(m_run[qt][r] - mn[r]);
        m_run[qt][r] = mn[r];
        lt[r] = 0.f;
      }
#pragma unroll
      for (int ct = 0; ct < 4; ct++)
#pragma unroll
        for (int r = 0; r < 4; r++){
          float p = __builtin_amdgcn_exp2f(s[qt][ct][r] - mn[r]);
          lt[r] += p;
          int qrow = qt * 16 + ((lane >> 4) << 2) + r;
          int t = ct * 16 + (lane & 15);
          int cc = t >> 3;
          Ps[w][qrow * 64 + (((cc ^ (qrow & 7)) << 3) | (t & 7))] = f2bf(p);
        }
#pragma unroll
      for (int r = 0; r < 4; r++){
        lt[r] += __shfl_xor(lt[r], 1);
        lt[r] += __shfl_xor(lt[r], 2);
        lt[r] += __shfl_xor(lt[r], 4);
        lt[r] += __shfl_xor(lt[r], 8);
        l_run[qt][r] = l_run[qt][r] * sc[r] + lt[r];
      }
#pragma unroll
      for (int nc = 0; nc < 4; nc++)
#pragma unroll
        for (int r = 0; r < 4; r++) o[qt][nc][r] *= sc[r];
    }
    // ---- PV: O += P * V ----
#pragma unroll
    for (int kc = 0; kc < 2; kc++){
      s16x8 pa[2];
#pragma unroll
      for (int qt = 0; qt < 2; qt++){
        int qrow = qt * 16 + (lane & 15);
        int c = kc * 4 + (lane >> 4);
        pa[qt] = *(const s16x8*)&Ps[w][qrow * 64 + ((c ^ (qrow & 7)) << 3)];
      }
#pragma unroll
      for (int nc = 0; nc < 4; nc++){
        int e = nc * 16 + (lane & 15);
        int c = kc * 4 + (lane >> 4);
        s16x8 vb = *(const s16x8*)&Vc[e * 64 + ((c ^ (e & 7)) << 3)];
#pragma unroll
        for (int qt = 0; qt < 2; qt++)
          o[qt][nc] = __builtin_amdgcn_mfma_f32_16x16x32_bf16(pa[qt], vb, o[qt][nc], 0, 0, 0);
      }
    }
    __syncthreads();
    cur ^= 1;
  }
#undef STAGE
#pragma unroll
  for (int qt = 0; qt < 2; qt++){
    float inv[4];
#pragma unroll
    for (int r = 0; r < 4; r++) inv[r] = 1.0f / l_run[qt][r];
#pragma unroll
    for (int nc = 0; nc < 4; nc++)
#pragma unroll
      for (int r = 0; r < 4; r++){
        int row = q0 + qt * 16 + ((lane >> 4) << 2) + r;
        int col = h * 64 + nc * 16 + (lane & 15);
        concat[(size_t)row * DMODEL + col] = f2bf(o[qt][nc][r] * inv[r]);
      }
  }
}

extern "C" void kernel_launch(void* const* d_in, const int* in_sizes, int n_in,
                              void* d_out, int out_size, void* d_ws, size_t ws_size,
                              hipStream_t stream){
  const float* x  = (const float*)d_in[0];
  const float* wq = (const float*)d_in[1];
  const float* bq = (const float*)d_in[2];
  const float* wk = (const float*)d_in[3];
  const float* bk = (const float*)d_in[4];
  const float* wv = (const float*)d_in[5];
  const float* bv = (const float*)d_in[6];
  const float* wo = (const float*)d_in[7];
  const float* bo = (const float*)d_in[8];
  char* ws = (char*)d_ws;
  // layout (bytes): xb/vT 8.39M | wqkvt 6.29M | wot 2.10M | biasq 12K(+pad) | qkv 25.2M | concat 8.39M
  unsigned short* xb     = (unsigned short*)(ws + 0);       // reused as vT after QKV GEMM
  unsigned short* wqkvt  = (unsigned short*)(ws + 8388608);
  unsigned short* wot    = (unsigned short*)(ws + 14680064);
  float*          biasq  = (float*)(ws + 16777216);
  unsigned short* qkv    = (unsigned short*)(ws + 16842752);
  unsigned short* concat = (unsigned short*)(ws + 42008576);
  unsigned short* vT     = xb;
  float* out = (float*)d_out;

  pack_x_kern<<<4096, 256, 0, stream>>>(x, xb);
  pack_wqkv_kern<<<12288, 256, 0, stream>>>(wq, bq, wk, bk, wv, bv, wqkvt, biasq);
  pack_wo_kern<<<4096, 256, 0, stream>>>(wo, wot);
  gemm_bt<true><<<dim3(24, 32), 256, 0, stream>>>(xb, wqkvt, biasq, qkv, 4096, 3072, 1024);
  transpose_v_kern<<<dim3(64, 16), 256, 0, stream>>>(qkv, vT);
  attn_kern<<<dim3(32, 16), 256, 0, stream>>>(qkv, vT, concat);
  gemm_bt<false><<<dim3(8, 32), 256, 0, stream>>>(concat, wot, bo, out, 4096, 1024, 1024);
}

// Round 5
// 235.801 us; speedup vs baseline: 1.7832x; 1.3351x over previous
//
#include <hip/hip_runtime.h>

#define S_LEN 4096
#define DMODEL 1024
#define NQKV 3072
#define NHEAD 16

typedef __attribute__((ext_vector_type(8))) short s16x8;
typedef __attribute__((ext_vector_type(4))) float f32x4;

__device__ inline unsigned short f2bf(float f){
  unsigned u = __builtin_bit_cast(unsigned, f);
  u += 0x7FFFu + ((u >> 16) & 1u);
  return (unsigned short)(u >> 16);
}

__device__ inline void gload_lds16(const void* g, void* l){
  __builtin_amdgcn_global_load_lds(
    (const __attribute__((address_space(1))) void*)g,
    (__attribute__((address_space(3))) void*)l, 16, 0, 0);
}

// ---- pack: x fp32 -> bf16 ----
__global__ __launch_bounds__(256) void pack_x_kern(const float* __restrict__ x,
                                                   unsigned short* __restrict__ xb){
  int i = (blockIdx.x * 256 + threadIdx.x) * 4;
  float4 v = *(const float4*)(x + i);
  ushort4 o;
  o.x = f2bf(v.x); o.y = f2bf(v.y); o.z = f2bf(v.z); o.w = f2bf(v.w);
  *(ushort4*)(xb + i) = o;
}

// ---- pack: wq/wk/wv [H][D][Dh] -> wt [3072][1024] (B^T layout), bias [3072] ----
__global__ __launch_bounds__(256) void pack_wqkv_kern(
    const float* __restrict__ wq, const float* __restrict__ bq,
    const float* __restrict__ wk, const float* __restrict__ bk,
    const float* __restrict__ wv, const float* __restrict__ bv,
    unsigned short* __restrict__ wt, float* __restrict__ bias){
  int idx = blockIdx.x * 256 + threadIdx.x;
  int which = idx >> 20;
  int rem = idx & 1048575;
  int e = rem & 63;
  int d = (rem >> 6) & 1023;
  int h = rem >> 16;
  const float* w = which == 0 ? wq : which == 1 ? wk : wv;
  const float* b = which == 0 ? bq : which == 1 ? bk : bv;
  float scale = which == 0 ? 0.18033688011112042f : 1.0f;  // 0.125 * log2(e)
  float val = w[(h * 1024 + d) * 64 + e] * scale;
  int n = which * 1024 + h * 64 + e;
  wt[(size_t)n * 1024 + d] = f2bf(val);
  if (d == 0) bias[n] = b[h * 64 + e] * scale;
}

// ---- pack: wo [D][D] -> wot [N][K] bf16 ----
__global__ __launch_bounds__(256) void pack_wo_kern(const float* __restrict__ wo,
                                                    unsigned short* __restrict__ wot){
  int idx = blockIdx.x * 256 + threadIdx.x;
  int n = idx & 1023, d = idx >> 10;
  wot[(size_t)n * 1024 + d] = f2bf(wo[(size_t)d * 1024 + n]);
}

// ---- transpose V columns of qkv: qkv[t][2048+c] -> vT[c][perm(t)] ----
// Within each 64-element t-block, storage position p = 32*kk + 8*g + j holds
// t = 32*kk + 16*(j>>2) + 4*g + (j&3)   (bit-shuffle bijection), so the attention
// PV step's A-side V fragment (r2-verified chunk indexing c=kk*4+g) pairs with a
// lane-local P B-fragment built directly from the QK^T accumulator registers.
__global__ __launch_bounds__(256) void transpose_v_kern(const unsigned short* __restrict__ qkv,
                                                        unsigned short* __restrict__ vT){
  __shared__ unsigned short tile[64][65];
  int t0 = blockIdx.x * 64, c0 = blockIdx.y * 64;
  int tid = threadIdx.x;
  int r = tid >> 2;
#pragma unroll
  for (int p = 0; p < 2; p++){
    int col = (tid & 3) * 16 + p * 8;
    s16x8 v = *(const s16x8*)&qkv[(size_t)(t0 + r) * NQKV + 2048 + c0 + col];
#pragma unroll
    for (int j = 0; j < 8; j++) tile[r][col + j] = (unsigned short)v[j];
  }
  __syncthreads();
  int c = tid >> 2;
#pragma unroll
  for (int p = 0; p < 2; p++){
    int tt = (tid & 3) * 16 + p * 8;   // multiple of 8: 32*kk + 8*g
    int kk32 = tt & 32;
    int g4 = (tt >> 1) & 12;           // 4*g
    union { s16x8 v; unsigned short a[8]; } u;
#pragma unroll
    for (int j = 0; j < 8; j++)
      u.a[j] = tile[kk32 + ((j >> 2) << 4) + g4 + (j & 3)][c];
    *(s16x8*)&vT[(size_t)(c0 + c) * S_LEN + t0 + tt] = u.v;
  }
}

// ---- bf16 MFMA GEMM: C[M,N] = A[M,K] * Bt[N,K]^T + bias, 128x128 tile, BK=64 ----
template <bool OUT_BF16>
__global__ __launch_bounds__(256) void gemm_bt(const unsigned short* __restrict__ A,
                                               const unsigned short* __restrict__ Bt,
                                               const float* __restrict__ bias,
                                               void* __restrict__ Cout,
                                               int M, int N, int K){
  __shared__ unsigned short As[128 * 64];
  __shared__ unsigned short Bs[128 * 64];
  int tid = threadIdx.x;
  int lane = tid & 63, w = tid >> 6;
  int wr = w >> 1, wc = w & 1;
  int m0 = blockIdx.y * 128, n0 = blockIdx.x * 128;
  f32x4 zero = {0.f, 0.f, 0.f, 0.f};
  f32x4 acc[4][4];
#pragma unroll
  for (int i = 0; i < 4; i++)
#pragma unroll
    for (int j = 0; j < 4; j++) acc[i][j] = zero;

  for (int ks = 0; ks < K; ks += 64){
#pragma unroll
    for (int i = 0; i < 4; i++){
      int u = i * 256 + tid;
      int row = u >> 3, c = u & 7;
      gload_lds16(A + ((size_t)(m0 + row) * K + ks + ((c ^ (row & 7)) << 3)), &As[u * 8]);
    }
#pragma unroll
    for (int i = 0; i < 4; i++){
      int u = i * 256 + tid;
      int row = u >> 3, c = u & 7;
      gload_lds16(Bt + ((size_t)(n0 + row) * K + ks + ((c ^ (row & 7)) << 3)), &Bs[u * 8]);
    }
    __syncthreads();
#pragma unroll
    for (int kk = 0; kk < 2; kk++){
      s16x8 af[4], bfr[4];
#pragma unroll
      for (int i = 0; i < 4; i++){
        int ra = wr * 64 + i * 16 + (lane & 15);
        int ca = kk * 4 + (lane >> 4);
        af[i] = *(const s16x8*)&As[ra * 64 + ((ca ^ (ra & 7)) << 3)];
        int rb = wc * 64 + i * 16 + (lane & 15);
        bfr[i] = *(const s16x8*)&Bs[rb * 64 + ((ca ^ (rb & 7)) << 3)];
      }
#pragma unroll
      for (int i = 0; i < 4; i++)
#pragma unroll
        for (int j = 0; j < 4; j++)
          acc[i][j] = __builtin_amdgcn_mfma_f32_16x16x32_bf16(af[i], bfr[j], acc[i][j], 0, 0, 0);
    }
    __syncthreads();
  }
#pragma unroll
  for (int i = 0; i < 4; i++)
#pragma unroll
    for (int j = 0; j < 4; j++){
      int col = n0 + wc * 64 + j * 16 + (lane & 15);
      float bv = bias[col];
#pragma unroll
      for (int r = 0; r < 4; r++){
        int row = m0 + wr * 64 + i * 16 + ((lane >> 4) << 2) + r;
        float v = acc[i][j][r] + bv;
        if (OUT_BF16) ((unsigned short*)Cout)[(size_t)row * N + col] = f2bf(v);
        else          ((float*)Cout)[(size_t)row * N + col] = v;
      }
    }
}

// ---- flash attention v5: 4 waves x 32 q-rows, 16x16 MFMA (r2-verified layouts),
//      swapped QK^T (S^T = K * Q^T), in-register softmax, lane-local P-pack ----
__global__ __launch_bounds__(256) void attn_kern(const unsigned short* __restrict__ qkv,
                                                 const unsigned short* __restrict__ vT,
                                                 unsigned short* __restrict__ concat){
  __shared__ unsigned short lds[16384];  // K dbuf @0,@4096 ; V dbuf @8192,@12288 (shorts)
  int tid = threadIdx.x, lane = tid & 63, w = tid >> 6;
  int q16 = lane & 15, g = lane >> 4;
  int h = blockIdx.y;
  int q0 = blockIdx.x * 128 + w * 32;
  // Q B-frags (r2's exact qa expression): lane supplies col q=q16, k-slots d = kk*32 + 8g + j
  s16x8 qb[2][2];
#pragma unroll
  for (int qt = 0; qt < 2; qt++)
#pragma unroll
    for (int kk = 0; kk < 2; kk++)
      qb[qt][kk] = *(const s16x8*)&qkv[(size_t)(q0 + qt * 16 + q16) * NQKV + h * 64 + kk * 32 + g * 8];
  f32x4 zero = {0.f, 0.f, 0.f, 0.f};
  f32x4 o[2][4];
  float m_run[2] = {-1e30f, -1e30f}, l_run[2] = {0.f, 0.f};
#pragma unroll
  for (int qt = 0; qt < 2; qt++)
#pragma unroll
    for (int nc = 0; nc < 4; nc++) o[qt][nc] = zero;

#define STAGE(buf, kt) do { \
    int t0_ = (kt) * 64; \
    _Pragma("unroll") \
    for (int i_ = 0; i_ < 2; i_++){ \
      int u_ = i_ * 256 + tid; \
      int row_ = u_ >> 3, c_ = u_ & 7; \
      gload_lds16(&qkv[(size_t)(t0_ + row_) * NQKV + 1024 + h * 64 + ((c_ ^ (row_ & 7)) << 3)], &lds[(buf) * 4096 + u_ * 8]); \
      gload_lds16(&vT[(size_t)(h * 64 + row_) * S_LEN + t0_ + ((c_ ^ (row_ & 7)) << 3)], &lds[8192 + (buf) * 4096 + u_ * 8]); \
    } } while (0)

  STAGE(0, 0);
  __syncthreads();
  int cur = 0;
  for (int kt = 0; kt < S_LEN / 64; kt++){
    if (kt + 1 < S_LEN / 64) STAGE(cur ^ 1, kt + 1);
    const unsigned short* Kc = &lds[cur * 4096];
    const unsigned short* Vc = &lds[8192 + cur * 4096];
    // ---- S^T = K * Q^T : s[qt][ct][r] = S[q=q16][t = 16ct + 4g + r] ----
    f32x4 s[2][4];
#pragma unroll
    for (int qt = 0; qt < 2; qt++)
#pragma unroll
      for (int ct = 0; ct < 4; ct++) s[qt][ct] = zero;
#pragma unroll
    for (int ct = 0; ct < 4; ct++)
#pragma unroll
      for (int kk = 0; kk < 2; kk++){
        int tr = ct * 16 + q16;
        int c = kk * 4 + g;
        s16x8 kf = *(const s16x8*)&Kc[tr * 64 + ((c ^ (tr & 7)) << 3)];
#pragma unroll
        for (int qt = 0; qt < 2; qt++)
          s[qt][ct] = __builtin_amdgcn_mfma_f32_16x16x32_bf16(kf, qb[qt][kk], s[qt][ct], 0, 0, 0);
      }
    // ---- online softmax (base-2); each q spans 4 lanes (g=0..3): 2 shfl steps ----
    float scq[2];
#pragma unroll
    for (int qt = 0; qt < 2; qt++){
      float pm = s[qt][0][0];
#pragma unroll
      for (int ct = 0; ct < 4; ct++)
#pragma unroll
        for (int r = 0; r < 4; r++) pm = fmaxf(pm, s[qt][ct][r]);
      pm = fmaxf(pm, __shfl_xor(pm, 16));
      pm = fmaxf(pm, __shfl_xor(pm, 32));
      float mn = fmaxf(m_run[qt], pm);
      float sc = __builtin_amdgcn_exp2f(m_run[qt] - mn);
      m_run[qt] = mn;
      float lt = 0.f;
#pragma unroll
      for (int ct = 0; ct < 4; ct++)
#pragma unroll
        for (int r = 0; r < 4; r++){
          float p = __builtin_amdgcn_exp2f(s[qt][ct][r] - mn);
          s[qt][ct][r] = p;
          lt += p;
        }
      lt += __shfl_xor(lt, 16);
      lt += __shfl_xor(lt, 32);
      l_run[qt] = l_run[qt] * sc + lt;
      scq[qt] = sc;
#pragma unroll
      for (int nc = 0; nc < 4; nc++)
#pragma unroll
        for (int r = 0; r < 4; r++) o[qt][nc][r] *= sc;
    }
    // ---- P -> bf16 B-frags, lane-local: pb[qt][kk].elem[j] = P[t = 32kk + 16(j>>2) + 4g + (j&3)]
    //      = s[qt][2kk + (j>>2)][j&3]  (matches vT's permuted storage on the A side) ----
    s16x8 pb[2][2];
#pragma unroll
    for (int qt = 0; qt < 2; qt++)
#pragma unroll
      for (int kk = 0; kk < 2; kk++){
        union { unsigned u[4]; s16x8 v; } pk;
#pragma unroll
        for (int i = 0; i < 4; i++){
          int ct = 2 * kk + (i >> 1);
          int r = (i & 1) * 2;
          pk.u[i] = (unsigned)f2bf(s[qt][ct][r]) | ((unsigned)f2bf(s[qt][ct][r + 1]) << 16);
        }
        pb[qt][kk] = pk.v;
      }
    // ---- O^T += V^T * P^T : A-side = vT rows (r2's af indexing) ----
#pragma unroll
    for (int nc = 0; nc < 4; nc++)
#pragma unroll
      for (int kk = 0; kk < 2; kk++){
        int er = nc * 16 + q16;
        int c = kk * 4 + g;
        s16x8 vf = *(const s16x8*)&Vc[er * 64 + ((c ^ (er & 7)) << 3)];
#pragma unroll
        for (int qt = 0; qt < 2; qt++)
          o[qt][nc] = __builtin_amdgcn_mfma_f32_16x16x32_bf16(vf, pb[qt][kk], o[qt][nc], 0, 0, 0);
      }
    __syncthreads();
    cur ^= 1;
  }
#undef STAGE
  // ---- epilogue: o[qt][nc][r] = O[q = q0+qt*16+q16][e = 16nc + 4g + r]; paired u32 stores ----
#pragma unroll
  for (int qt = 0; qt < 2; qt++){
    float inv = 1.0f / l_run[qt];
    size_t row = (size_t)(q0 + qt * 16 + q16);
#pragma unroll
    for (int nc = 0; nc < 4; nc++)
#pragma unroll
      for (int rp = 0; rp < 4; rp += 2){
        unsigned pkv = (unsigned)f2bf(o[qt][nc][rp] * inv) |
                       ((unsigned)f2bf(o[qt][nc][rp + 1] * inv) << 16);
        *(unsigned*)&concat[row * DMODEL + h * 64 + nc * 16 + 4 * g + rp] = pkv;
      }
  }
}

extern "C" void kernel_launch(void* const* d_in, const int* in_sizes, int n_in,
                              void* d_out, int out_size, void* d_ws, size_t ws_size,
                              hipStream_t stream){
  const float* x  = (const float*)d_in[0];
  const float* wq = (const float*)d_in[1];
  const float* bq = (const float*)d_in[2];
  const float* wk = (const float*)d_in[3];
  const float* bk = (const float*)d_in[4];
  const float* wv = (const float*)d_in[5];
  const float* bv = (const float*)d_in[6];
  const float* wo = (const float*)d_in[7];
  const float* bo = (const float*)d_in[8];
  char* ws = (char*)d_ws;
  unsigned short* xb     = (unsigned short*)(ws + 0);       // reused as vT after QKV GEMM
  unsigned short* wqkvt  = (unsigned short*)(ws + 8388608);
  unsigned short* wot    = (unsigned short*)(ws + 14680064);
  float*          biasq  = (float*)(ws + 16777216);
  unsigned short* qkv    = (unsigned short*)(ws + 16842752);
  unsigned short* concat = (unsigned short*)(ws + 42008576);
  unsigned short* vT     = xb;
  float* out = (float*)d_out;

  pack_x_kern<<<4096, 256, 0, stream>>>(x, xb);
  pack_wqkv_kern<<<12288, 256, 0, stream>>>(wq, bq, wk, bk, wv, bv, wqkvt, biasq);
  pack_wo_kern<<<4096, 256, 0, stream>>>(wo, wot);
  gemm_bt<true><<<dim3(24, 32), 256, 0, stream>>>(xb, wqkvt, biasq, qkv, 4096, 3072, 1024);
  transpose_v_kern<<<dim3(64, 16), 256, 0, stream>>>(qkv, vT);
  attn_kern<<<dim3(32, 16), 256, 0, stream>>>(qkv, vT, concat);
  gemm_bt<false><<<dim3(8, 32), 256, 0, stream>>>(concat, wot, bo, out, 4096, 1024, 1024);
}

// Round 7
// 219.142 us; speedup vs baseline: 1.9188x; 1.0760x over previous
//
#include <hip/hip_runtime.h>
#include <hip/hip_bf16.h>

#define S_LEN 4096
#define DMODEL 1024
#define NQKV 3072
#define NHEAD 16

typedef __attribute__((ext_vector_type(8))) short s16x8;
typedef __attribute__((ext_vector_type(4))) float f32x4;

__device__ inline unsigned short f2bf(float f){
  unsigned u = __builtin_bit_cast(unsigned, f);
  u += 0x7FFFu + ((u >> 16) & 1u);
  return (unsigned short)(u >> 16);
}

// hardware packed f32x2 -> bf16x2 (RNE); low 16 bits = first arg
__device__ inline unsigned pk2bf(float a, float b){
  float2 t; t.x = a; t.y = b;
  __hip_bfloat162 h = __float22bfloat162_rn(t);
  unsigned r;
  __builtin_memcpy(&r, &h, 4);
  return r;
}

__device__ inline void gload_lds16(const void* g, void* l){
  __builtin_amdgcn_global_load_lds(
    (const __attribute__((address_space(1))) void*)g,
    (__attribute__((address_space(3))) void*)l, 16, 0, 0);
}

// ---- pack: x fp32 -> bf16 ----
__global__ __launch_bounds__(256) void pack_x_kern(const float* __restrict__ x,
                                                   unsigned short* __restrict__ xb){
  int i = (blockIdx.x * 256 + threadIdx.x) * 4;
  float4 v = *(const float4*)(x + i);
  ushort4 o;
  o.x = f2bf(v.x); o.y = f2bf(v.y); o.z = f2bf(v.z); o.w = f2bf(v.w);
  *(ushort4*)(xb + i) = o;
}

// ---- pack: wq/wk/wv [H][D][Dh] -> wt [3072][1024] (B^T layout), bias [3072] ----
__global__ __launch_bounds__(256) void pack_wqkv_kern(
    const float* __restrict__ wq, const float* __restrict__ bq,
    const float* __restrict__ wk, const float* __restrict__ bk,
    const float* __restrict__ wv, const float* __restrict__ bv,
    unsigned short* __restrict__ wt, float* __restrict__ bias){
  int idx = blockIdx.x * 256 + threadIdx.x;
  int which = idx >> 20;
  int rem = idx & 1048575;
  int e = rem & 63;
  int d = (rem >> 6) & 1023;
  int h = rem >> 16;
  const float* w = which == 0 ? wq : which == 1 ? wk : wv;
  const float* b = which == 0 ? bq : which == 1 ? bk : bv;
  float scale = which == 0 ? 0.18033688011112042f : 1.0f;  // 0.125 * log2(e)
  float val = w[(h * 1024 + d) * 64 + e] * scale;
  int n = which * 1024 + h * 64 + e;
  wt[(size_t)n * 1024 + d] = f2bf(val);
  if (d == 0) bias[n] = b[h * 64 + e] * scale;
}

// ---- pack: wo [D][D] -> wot [N][K] bf16 ----
__global__ __launch_bounds__(256) void pack_wo_kern(const float* __restrict__ wo,
                                                    unsigned short* __restrict__ wot){
  int idx = blockIdx.x * 256 + threadIdx.x;
  int n = idx & 1023, d = idx >> 10;
  wot[(size_t)n * 1024 + d] = f2bf(wo[(size_t)d * 1024 + n]);
}

// ---- transpose V columns of qkv: qkv[t][2048+c] -> vT[c][perm(t)] ----
// Within each 64-element t-block, storage position p = 32*kk + 8*g + j holds
// t = 32*kk + 16*(j>>2) + 4*g + (j&3)  (bit-shuffle bijection) so the attention
// PV step's lane-local P B-fragment pairs with the A-side V fragment.
__global__ __launch_bounds__(256) void transpose_v_kern(const unsigned short* __restrict__ qkv,
                                                        unsigned short* __restrict__ vT){
  __shared__ unsigned short tile[64][65];
  int t0 = blockIdx.x * 64, c0 = blockIdx.y * 64;
  int tid = threadIdx.x;
  int r = tid >> 2;
#pragma unroll
  for (int p = 0; p < 2; p++){
    int col = (tid & 3) * 16 + p * 8;
    s16x8 v = *(const s16x8*)&qkv[(size_t)(t0 + r) * NQKV + 2048 + c0 + col];
#pragma unroll
    for (int j = 0; j < 8; j++) tile[r][col + j] = (unsigned short)v[j];
  }
  __syncthreads();
  int c = tid >> 2;
#pragma unroll
  for (int p = 0; p < 2; p++){
    int tt = (tid & 3) * 16 + p * 8;   // 32*kk + 8*g
    int kk32 = tt & 32;
    int g4 = (tt >> 1) & 12;           // 4*g
    union { s16x8 v; unsigned short a[8]; } u;
#pragma unroll
    for (int j = 0; j < 8; j++)
      u.a[j] = tile[kk32 + ((j >> 2) << 4) + g4 + (j & 3)][c];
    *(s16x8*)&vT[(size_t)(c0 + c) * S_LEN + t0 + tt] = u.v;
  }
}

// ---- bf16 MFMA GEMM: C[M,N] = A[M,K] * Bt[N,K]^T + bias, 128x128 tile, BK=64 ----
template <bool OUT_BF16>
__global__ __launch_bounds__(256) void gemm_bt(const unsigned short* __restrict__ A,
                                               const unsigned short* __restrict__ Bt,
                                               const float* __restrict__ bias,
                                               void* __restrict__ Cout,
                                               int M, int N, int K){
  __shared__ unsigned short As[128 * 64];
  __shared__ unsigned short Bs[128 * 64];
  int tid = threadIdx.x;
  int lane = tid & 63, w = tid >> 6;
  int wr = w >> 1, wc = w & 1;
  int m0 = blockIdx.y * 128, n0 = blockIdx.x * 128;
  f32x4 zero = {0.f, 0.f, 0.f, 0.f};
  f32x4 acc[4][4];
#pragma unroll
  for (int i = 0; i < 4; i++)
#pragma unroll
    for (int j = 0; j < 4; j++) acc[i][j] = zero;

  for (int ks = 0; ks < K; ks += 64){
#pragma unroll
    for (int i = 0; i < 4; i++){
      int u = i * 256 + tid;
      int row = u >> 3, c = u & 7;
      gload_lds16(A + ((size_t)(m0 + row) * K + ks + ((c ^ (row & 7)) << 3)), &As[u * 8]);
    }
#pragma unroll
    for (int i = 0; i < 4; i++){
      int u = i * 256 + tid;
      int row = u >> 3, c = u & 7;
      gload_lds16(Bt + ((size_t)(n0 + row) * K + ks + ((c ^ (row & 7)) << 3)), &Bs[u * 8]);
    }
    __syncthreads();
#pragma unroll
    for (int kk = 0; kk < 2; kk++){
      s16x8 af[4], bfr[4];
#pragma unroll
      for (int i = 0; i < 4; i++){
        int ra = wr * 64 + i * 16 + (lane & 15);
        int ca = kk * 4 + (lane >> 4);
        af[i] = *(const s16x8*)&As[ra * 64 + ((ca ^ (ra & 7)) << 3)];
        int rb = wc * 64 + i * 16 + (lane & 15);
        bfr[i] = *(const s16x8*)&Bs[rb * 64 + ((ca ^ (rb & 7)) << 3)];
      }
#pragma unroll
      for (int i = 0; i < 4; i++)
#pragma unroll
        for (int j = 0; j < 4; j++)
          acc[i][j] = __builtin_amdgcn_mfma_f32_16x16x32_bf16(af[i], bfr[j], acc[i][j], 0, 0, 0);
    }
    __syncthreads();
  }
#pragma unroll
  for (int i = 0; i < 4; i++)
#pragma unroll
    for (int j = 0; j < 4; j++){
      int col = n0 + wc * 64 + j * 16 + (lane & 15);
      float bv = bias[col];
#pragma unroll
      for (int r = 0; r < 4; r++){
        int row = m0 + wr * 64 + i * 16 + ((lane >> 4) << 2) + r;
        float v = acc[i][j][r] + bv;
        if (OUT_BF16) ((unsigned short*)Cout)[(size_t)row * N + col] = f2bf(v);
        else          ((float*)Cout)[(size_t)row * N + col] = v;
      }
    }
}

// ---- flash attention v6: r5 structure + hw cvt_pk pack + defer-max rescale ----
__global__ __launch_bounds__(256) void attn_kern(const unsigned short* __restrict__ qkv,
                                                 const unsigned short* __restrict__ vT,
                                                 unsigned short* __restrict__ concat){
  __shared__ unsigned short lds[16384];  // K dbuf @0,@4096 ; V dbuf @8192,@12288 (shorts)
  int tid = threadIdx.x, lane = tid & 63, w = tid >> 6;
  int q16 = lane & 15, g = lane >> 4;
  int h = blockIdx.y;
  int q0 = blockIdx.x * 128 + w * 32;
  // Q B-frags: lane supplies col q=q16, k-slots d = kk*32 + 8g + j (pre-scaled by 0.125*log2e)
  s16x8 qb[2][2];
#pragma unroll
  for (int qt = 0; qt < 2; qt++)
#pragma unroll
    for (int kk = 0; kk < 2; kk++)
      qb[qt][kk] = *(const s16x8*)&qkv[(size_t)(q0 + qt * 16 + q16) * NQKV + h * 64 + kk * 32 + g * 8];
  f32x4 zero = {0.f, 0.f, 0.f, 0.f};
  f32x4 o[2][4];
  float m_run[2] = {-1e30f, -1e30f}, l_run[2] = {0.f, 0.f};
#pragma unroll
  for (int qt = 0; qt < 2; qt++)
#pragma unroll
    for (int nc = 0; nc < 4; nc++) o[qt][nc] = zero;

#define STAGE(buf, kt) do { \
    int t0_ = (kt) * 64; \
    _Pragma("unroll") \
    for (int i_ = 0; i_ < 2; i_++){ \
      int u_ = i_ * 256 + tid; \
      int row_ = u_ >> 3, c_ = u_ & 7; \
      gload_lds16(&qkv[(size_t)(t0_ + row_) * NQKV + 1024 + h * 64 + ((c_ ^ (row_ & 7)) << 3)], &lds[(buf) * 4096 + u_ * 8]); \
      gload_lds16(&vT[(size_t)(h * 64 + row_) * S_LEN + t0_ + ((c_ ^ (row_ & 7)) << 3)], &lds[8192 + (buf) * 4096 + u_ * 8]); \
    } } while (0)

  STAGE(0, 0);
  __syncthreads();
  int cur = 0;
  for (int kt = 0; kt < S_LEN / 64; kt++){
    if (kt + 1 < S_LEN / 64) STAGE(cur ^ 1, kt + 1);
    const unsigned short* Kc = &lds[cur * 4096];
    const unsigned short* Vc = &lds[8192 + cur * 4096];
    // ---- S^T = K * Q^T : s[qt][ct][r] = S[q=q16][t = 16ct + 4g + r] ----
    f32x4 s[2][4];
#pragma unroll
    for (int qt = 0; qt < 2; qt++)
#pragma unroll
      for (int ct = 0; ct < 4; ct++) s[qt][ct] = zero;
#pragma unroll
    for (int ct = 0; ct < 4; ct++)
#pragma unroll
      for (int kk = 0; kk < 2; kk++){
        int tr = ct * 16 + q16;
        int c = kk * 4 + g;
        s16x8 kf = *(const s16x8*)&Kc[tr * 64 + ((c ^ (tr & 7)) << 3)];
#pragma unroll
        for (int qt = 0; qt < 2; qt++)
          s[qt][ct] = __builtin_amdgcn_mfma_f32_16x16x32_bf16(kf, qb[qt][kk], s[qt][ct], 0, 0, 0);
      }
    // ---- tile max (tree), per q spread over 4 lanes (g) ----
    float pm[2];
#pragma unroll
    for (int qt = 0; qt < 2; qt++){
      float a0 = fmaxf(fmaxf(s[qt][0][0], s[qt][0][1]), fmaxf(s[qt][0][2], s[qt][0][3]));
      float a1 = fmaxf(fmaxf(s[qt][1][0], s[qt][1][1]), fmaxf(s[qt][1][2], s[qt][1][3]));
      float a2 = fmaxf(fmaxf(s[qt][2][0], s[qt][2][1]), fmaxf(s[qt][2][2], s[qt][2][3]));
      float a3 = fmaxf(fmaxf(s[qt][3][0], s[qt][3][1]), fmaxf(s[qt][3][2], s[qt][3][3]));
      float p = fmaxf(fmaxf(a0, a1), fmaxf(a2, a3));
      p = fmaxf(p, __shfl_xor(p, 16));
      p = fmaxf(p, __shfl_xor(p, 32));
      pm[qt] = p;
    }
    // ---- defer-max: only rescale when the tile max meaningfully exceeds m_run ----
    if (!__all((pm[0] <= m_run[0] + 8.f) && (pm[1] <= m_run[1] + 8.f))){
#pragma unroll
      for (int qt = 0; qt < 2; qt++){
        float mn = fmaxf(m_run[qt], pm[qt]);
        float sc = __builtin_amdgcn_exp2f(m_run[qt] - mn);
        m_run[qt] = mn;
        l_run[qt] *= sc;
#pragma unroll
        for (int nc = 0; nc < 4; nc++)
#pragma unroll
          for (int r = 0; r < 4; r++) o[qt][nc][r] *= sc;
      }
    }
    // ---- exp2 + row-sum (tree) ----
#pragma unroll
    for (int qt = 0; qt < 2; qt++){
      float mn = m_run[qt];
#pragma unroll
      for (int ct = 0; ct < 4; ct++)
#pragma unroll
        for (int r = 0; r < 4; r++)
          s[qt][ct][r] = __builtin_amdgcn_exp2f(s[qt][ct][r] - mn);
      float b0 = (s[qt][0][0] + s[qt][0][1]) + (s[qt][0][2] + s[qt][0][3]);
      float b1 = (s[qt][1][0] + s[qt][1][1]) + (s[qt][1][2] + s[qt][1][3]);
      float b2 = (s[qt][2][0] + s[qt][2][1]) + (s[qt][2][2] + s[qt][2][3]);
      float b3 = (s[qt][3][0] + s[qt][3][1]) + (s[qt][3][2] + s[qt][3][3]);
      float lt = (b0 + b1) + (b2 + b3);
      lt += __shfl_xor(lt, 16);
      lt += __shfl_xor(lt, 32);
      l_run[qt] += lt;
    }
    // ---- P -> bf16 B-frags, lane-local (hw cvt_pk):
    //      pb[qt][kk].elem[j] = P[t = 32kk + 16(j>>2) + 4g + (j&3)] = s[qt][2kk+(j>>2)][j&3] ----
    s16x8 pb[2][2];
#pragma unroll
    for (int qt = 0; qt < 2; qt++)
#pragma unroll
      for (int kk = 0; kk < 2; kk++){
        union { unsigned u[4]; s16x8 v; } pk;
#pragma unroll
        for (int i = 0; i < 4; i++){
          int ct = 2 * kk + (i >> 1);
          int r = (i & 1) * 2;
          pk.u[i] = pk2bf(s[qt][ct][r], s[qt][ct][r + 1]);
        }
        pb[qt][kk] = pk.v;
      }
    // ---- O^T += V^T * P^T : A-side = vT rows ----
#pragma unroll
    for (int nc = 0; nc < 4; nc++)
#pragma unroll
      for (int kk = 0; kk < 2; kk++){
        int er = nc * 16 + q16;
        int c = kk * 4 + g;
        s16x8 vf = *(const s16x8*)&Vc[er * 64 + ((c ^ (er & 7)) << 3)];
#pragma unroll
        for (int qt = 0; qt < 2; qt++)
          o[qt][nc] = __builtin_amdgcn_mfma_f32_16x16x32_bf16(vf, pb[qt][kk], o[qt][nc], 0, 0, 0);
      }
    __syncthreads();
    cur ^= 1;
  }
#undef STAGE
  // ---- epilogue: o[qt][nc][r] = O[q = q0+qt*16+q16][e = 16nc + 4g + r]; paired u32 stores ----
#pragma unroll
  for (int qt = 0; qt < 2; qt++){
    float inv = 1.0f / l_run[qt];
    size_t row = (size_t)(q0 + qt * 16 + q16);
#pragma unroll
    for (int nc = 0; nc < 4; nc++)
#pragma unroll
      for (int rp = 0; rp < 4; rp += 2){
        unsigned pkv = pk2bf(o[qt][nc][rp] * inv, o[qt][nc][rp + 1] * inv);
        *(unsigned*)&concat[row * DMODEL + h * 64 + nc * 16 + 4 * g + rp] = pkv;
      }
  }
}

extern "C" void kernel_launch(void* const* d_in, const int* in_sizes, int n_in,
                              void* d_out, int out_size, void* d_ws, size_t ws_size,
                              hipStream_t stream){
  const float* x  = (const float*)d_in[0];
  const float* wq = (const float*)d_in[1];
  const float* bq = (const float*)d_in[2];
  const float* wk = (const float*)d_in[3];
  const float* bk = (const float*)d_in[4];
  const float* wv = (const float*)d_in[5];
  const float* bv = (const float*)d_in[6];
  const float* wo = (const float*)d_in[7];
  const float* bo = (const float*)d_in[8];
  char* ws = (char*)d_ws;
  unsigned short* xb     = (unsigned short*)(ws + 0);       // reused as vT after QKV GEMM
  unsigned short* wqkvt  = (unsigned short*)(ws + 8388608);
  unsigned short* wot    = (unsigned short*)(ws + 14680064);
  float*          biasq  = (float*)(ws + 16777216);
  unsigned short* qkv    = (unsigned short*)(ws + 16842752);
  unsigned short* concat = (unsigned short*)(ws + 42008576);
  unsigned short* vT     = xb;
  float* out = (float*)d_out;

  pack_x_kern<<<4096, 256, 0, stream>>>(x, xb);
  pack_wqkv_kern<<<12288, 256, 0, stream>>>(wq, bq, wk, bk, wv, bv, wqkvt, biasq);
  pack_wo_kern<<<4096, 256, 0, stream>>>(wo, wot);
  gemm_bt<true><<<dim3(24, 32), 256, 0, stream>>>(xb, wqkvt, biasq, qkv, 4096, 3072, 1024);
  transpose_v_kern<<<dim3(64, 16), 256, 0, stream>>>(qkv, vT);
  attn_kern<<<dim3(32, 16), 256, 0, stream>>>(qkv, vT, concat);
  gemm_bt<false><<<dim3(8, 32), 256, 0, stream>>>(concat, wot, bo, out, 4096, 1024, 1024);
}